// Round 1
// baseline (13003.992 us; speedup 1.0000x reference)
//
#include <hip/hip_runtime.h>
#include <math.h>

#define L 256
#define P 1024
#define P1 1025
#define TWOL 512
#define FOURL 1024
#define NATT 48
#define NLSTM 16
#define NBLK (NATT + NLSTM)
#define TPB 256

// workspace layout (float units)
#define OFF_VH    0
#define OFF_WHT   (OFF_VH + P1*L)              // 1025*256
#define OFF_GX    (OFF_WHT + P1*FOURL)         // 1025*1024
#define OFF_X2P   (OFF_GX + 2*NATT*FOURL)      // gx parts, 2 parities
#define OFF_HBUF  (OFF_X2P + 2*NLSTM*L)
#define OFF_CNT   (OFF_HBUF + 2*L)             // c_att @ +0, c_lstm @ +32 (float slots)
#define OFF_SP    (OFF_CNT + 64)               // S parts [2][48]
#define WS_FLOATS (OFF_SP + 2*NATT)

#define DYN_SMEM 118912  // att role: 23*256*4 + 23*1024*4 + 1024 + 128

__device__ __forceinline__ float fast_tanh(float x) {
  float u = __expf(2.0f * x);
  return 1.0f - 2.0f * __builtin_amdgcn_rcpf(1.0f + u);
}
__device__ __forceinline__ float sigm(float x) {
  return __builtin_amdgcn_rcpf(1.0f + __expf(-x));
}
__device__ __forceinline__ float wave_reduce(float v) {
  #pragma unroll
  for (int o = 32; o > 0; o >>= 1) v += __shfl_xor(v, o, 64);
  return v;
}

__global__ void init_kernel(float* __restrict__ ws) {
  const int tid = threadIdx.x;
  for (int idx = tid; idx < NLSTM * L; idx += TPB) ws[OFF_X2P + idx] = 0.0f; // parity-0 x2 parts
  for (int idx = tid; idx < L; idx += TPB) ws[OFF_HBUF + idx] = 0.0f;        // parity-0 h
  if (tid < 64) ws[OFF_CNT + tid] = 0.0f;                                    // counters (bits=0)
}

// C[j][n] = sum_k H_r[j][k] * W[n][k], with W = [W1 ; W_ih] (N=1280), H_r[1024][:] = 0
__global__ void __launch_bounds__(256) prep_gemm(const float* __restrict__ H,
                                                 const float* __restrict__ W1,
                                                 const float* __restrict__ W_ih,
                                                 float* __restrict__ ws) {
  __shared__ float As[32 * 64];
  __shared__ float Bs[64 * 33];
  const int tid = threadIdx.x;
  const int j0 = blockIdx.x * 64;
  const int n0 = blockIdx.y * 64;
  const int tx = tid & 15, ty = tid >> 4;
  float acc[4][4] = {{0.f,0.f,0.f,0.f},{0.f,0.f,0.f,0.f},{0.f,0.f,0.f,0.f},{0.f,0.f,0.f,0.f}};
  for (int ks = 0; ks < TWOL; ks += 32) {
    for (int idx = tid; idx < 2048; idx += 256) {
      int kk = idx >> 6, jj = idx & 63;
      int j = j0 + jj;
      As[kk * 64 + jj] = (j < P) ? H[(ks + kk) * P + j] : 0.0f;
    }
    for (int idx = tid; idx < 2048; idx += 256) {
      int kk = idx & 31, nn = idx >> 5;
      int n = n0 + nn;
      Bs[nn * 33 + kk] = (n < L) ? W1[n * TWOL + ks + kk] : W_ih[(n - L) * TWOL + ks + kk];
    }
    __syncthreads();
    #pragma unroll
    for (int kk = 0; kk < 32; ++kk) {
      float4 a = *(const float4*)&As[kk * 64 + ty * 4];
      #pragma unroll
      for (int r = 0; r < 4; ++r) {
        float bb = Bs[(tx * 4 + r) * 33 + kk];
        acc[r][0] += a.x * bb; acc[r][1] += a.y * bb;
        acc[r][2] += a.z * bb; acc[r][3] += a.w * bb;
      }
    }
    __syncthreads();
  }
  #pragma unroll
  for (int q = 0; q < 4; ++q) {
    int j = j0 + ty * 4 + q;
    if (j <= P) {
      float4 v = make_float4(acc[0][q], acc[1][q], acc[2][q], acc[3][q]);
      int n = n0 + tx * 4;
      if (n < L) *(float4*)&ws[OFF_VH + j * L + n] = v;
      else       *(float4*)&ws[OFF_WHT + j * FOURL + (n - L)] = v;
    }
  }
}

__global__ void __launch_bounds__(TPB, 1) scan_kernel(
    const float* __restrict__ W2, const float* __restrict__ b2,
    const float* __restrict__ w3, const float* __restrict__ cin,
    const float* __restrict__ W_hh, const float* __restrict__ b_ih,
    const float* __restrict__ b_hh,
    float* __restrict__ ws, float* __restrict__ out) {
  extern __shared__ float smem[];
  const int tid = threadIdx.x;
  const int b = blockIdx.x;
  float* gx   = ws + OFF_GX;
  float* x2p  = ws + OFF_X2P;
  float* hbuf = ws + OFF_HBUF;
  float* sp   = ws + OFF_SP;
  uint32_t* c_att  = (uint32_t*)(ws + OFF_CNT);
  uint32_t* c_lstm = (uint32_t*)(ws + OFF_CNT + 32);

  if (b < NATT) {
    // ---------------- attention role ----------------
    int nrows, j0;
    if (b < 32)      { nrows = 21; j0 = 21 * b; }
    else if (b < 47) { nrows = 22; j0 = 672 + 22 * (b - 32); }
    else             { nrows = 23; j0 = 1002; }            // includes terminal j=1024 (zero row)
    float* vh_s  = smem;                  // <=23*256
    float* wht_s = smem + 23 * L;         // <=23*1024
    float* x2_s  = wht_s + 23 * FOURL;    // 256
    float* e_s   = x2_s + L;              // 32
    const float* VH  = ws + OFF_VH;
    const float* WHT = ws + OFF_WHT;
    for (int idx = tid; idx < nrows * L; idx += TPB)     vh_s[idx]  = VH[j0 * L + idx];
    for (int idx = tid; idx < nrows * FOURL; idx += TPB) wht_s[idx] = WHT[j0 * FOURL + idx];
    const int lane = tid & 63, wid = tid >> 6;
    const float4 w3r = *(const float4*)&w3[4 * lane];
    const float rb2 = b2[tid];
    const float cb = cin[0];
    __syncthreads();

    for (int t = 0; t < P; ++t) {
      const int par = t & 1;
      if (t > 0) {
        if (tid == 0) {
          const uint32_t tgt = (uint32_t)(NLSTM * t);
          while (__hip_atomic_load(c_lstm, __ATOMIC_RELAXED, __HIP_MEMORY_SCOPE_AGENT) < tgt) {}
          __builtin_amdgcn_fence(__ATOMIC_ACQUIRE, "agent");
        }
        __syncthreads();
      }
      {  // x2 = b2 + sum of lstm partials
        float v = rb2;
        const float* xp = x2p + par * NLSTM * L;
        #pragma unroll
        for (int q = 0; q < NLSTM; ++q) v += xp[q * L + tid];
        x2_s[tid] = v;
      }
      __syncthreads();
      const float4 x2r = *(const float4*)&x2_s[4 * lane];
      for (int r = wid; r < nrows; r += 4) {
        float4 a = *(const float4*)&vh_s[r * L + 4 * lane];
        float s = w3r.x * fast_tanh(a.x + x2r.x);
        s += w3r.y * fast_tanh(a.y + x2r.y);
        s += w3r.z * fast_tanh(a.z + x2r.z);
        s += w3r.w * fast_tanh(a.w + x2r.w);
        s = wave_reduce(s);
        if (lane == 0) {
          float vf = s + cb;
          e_s[r] = __expf(vf);
          out[(t + 1) * P1 + j0 + r] = vf;   // raw logits; final kernel normalizes
        }
      }
      __syncthreads();
      {  // gate partial: this block's columns' contribution to all 1024 gate rows
        float4 acc = make_float4(0.f, 0.f, 0.f, 0.f);
        for (int r = 0; r < nrows; ++r) {
          float e = e_s[r];
          float4 w = *(const float4*)&wht_s[r * FOURL + 4 * tid];
          acc.x += e * w.x; acc.y += e * w.y; acc.z += e * w.z; acc.w += e * w.w;
        }
        *(float4*)&gx[(par * NATT + b) * FOURL + 4 * tid] = acc;
      }
      if (wid == 0) {  // S partial
        float e = (lane < nrows) ? e_s[lane] : 0.0f;
        e = wave_reduce(e);
        if (lane == 0) sp[par * NATT + b] = e;
      }
      __syncthreads();
      if (tid == 0) {
        __builtin_amdgcn_fence(__ATOMIC_RELEASE, "agent");
        __hip_atomic_fetch_add(c_att, 1u, __ATOMIC_RELAXED, __HIP_MEMORY_SCOPE_AGENT);
      }
    }
  } else {
    // ---------------- lstm role ----------------
    const int lidx = b - NATT;
    const int i0 = 16 * lidx;
    float* whh_s = smem;              // 64*256
    float* w2c_s = whh_s + 64 * L;    // 256*16
    float* h_s   = w2c_s + L * 16;    // 256
    float* hhp_s = h_s + L;           // 256
    float* hh_s  = hhp_s + L;         // 64
    float* gxp_s = hh_s + 64;         // 256
    float* gate_s= gxp_s + L;         // 64
    float* sarr_s= gate_s + 64;       // 48
    float* cc_s  = sarr_s + 48;       // 16
    float* hn_s  = cc_s + 16;         // 16
    for (int idx = tid; idx < 64 * L; idx += TPB) {
      int z = idx >> 8, k = idx & 255;
      int gr = (z >> 4) * L + i0 + (z & 15);
      whh_s[idx] = W_hh[gr * L + k];
    }
    for (int idx = tid; idx < L * 16; idx += TPB) {
      int k = idx >> 4, ii = idx & 15;
      w2c_s[idx] = W2[k * L + i0 + ii];
    }
    float biasz = 0.0f;
    if (tid < 64) {
      int gr = (tid >> 4) * L + i0 + (tid & 15);
      biasz = b_ih[gr] + b_hh[gr];
    }
    if (tid < 16) cc_s[tid] = 0.0f;
    __syncthreads();
    const int z = tid & 63, w = tid >> 6;

    for (int t = 0; t < P; ++t) {
      const int par = t & 1;
      if (t > 0) {
        if (tid == 0) {
          const uint32_t tgt = (uint32_t)(NLSTM * t);
          while (__hip_atomic_load(c_lstm, __ATOMIC_RELAXED, __HIP_MEMORY_SCOPE_AGENT) < tgt) {}
          __builtin_amdgcn_fence(__ATOMIC_ACQUIRE, "agent");
        }
        __syncthreads();
      }
      h_s[tid] = hbuf[par * L + tid];
      __syncthreads();
      {  // hh = W_hh @ h for my 64 gate rows (4 partial chunks, bank-skewed)
        float acc = 0.0f;
        #pragma unroll 8
        for (int m = 0; m < 64; ++m) {
          int k = w * 64 + ((m + z) & 63);
          acc += whh_s[z * L + k] * h_s[k];
        }
        hhp_s[w * 64 + z] = acc;
      }
      __syncthreads();
      if (tid < 64)
        hh_s[tid] = biasz + hhp_s[tid] + hhp_s[64 + tid] + hhp_s[128 + tid] + hhp_s[192 + tid];
      // wait for all attention partials of step t
      if (tid == 0) {
        const uint32_t tgt = (uint32_t)(NATT * (t + 1));
        while (__hip_atomic_load(c_att, __ATOMIC_RELAXED, __HIP_MEMORY_SCOPE_AGENT) < tgt) {}
        __builtin_amdgcn_fence(__ATOMIC_ACQUIRE, "agent");
      }
      __syncthreads();
      {  // gather gate partials for my rows
        const float* gxp = gx + par * NATT * FOURL;
        int gr = (z >> 4) * L + i0 + (z & 15);
        float acc = 0.0f;
        #pragma unroll
        for (int q = 12 * w; q < 12 * w + 12; ++q) acc += gxp[q * FOURL + gr];
        gxp_s[w * 64 + z] = acc;
      }
      if (tid < NATT) sarr_s[tid] = sp[par * NATT + tid];
      __syncthreads();
      if (tid < 64) {
        float S = 0.0f;
        #pragma unroll
        for (int q = 0; q < NATT; ++q) S += sarr_s[q];
        float gxv = gxp_s[tid] + gxp_s[64 + tid] + gxp_s[128 + tid] + gxp_s[192 + tid];
        gate_s[tid] = gxv * __builtin_amdgcn_rcpf(S) + hh_s[tid];
      }
      if (tid < 16) {  // same wave as gate_s writers: in-order LDS within a wave
        float gi = gate_s[tid], gf = gate_s[16 + tid], gg = gate_s[32 + tid], go = gate_s[48 + tid];
        float c_new = sigm(gf) * cc_s[tid] + sigm(gi) * fast_tanh(gg);
        float h_new = sigm(go) * fast_tanh(c_new);
        cc_s[tid] = c_new; hn_s[tid] = h_new;
        hbuf[((t + 1) & 1) * L + i0 + tid] = h_new;
      }
      __syncthreads();
      {  // x2 contribution for step t+1
        float acc = 0.0f;
        #pragma unroll
        for (int ii = 0; ii < 16; ++ii) acc += w2c_s[tid * 16 + ii] * hn_s[ii];
        x2p[(((t + 1) & 1) * NLSTM + lidx) * L + tid] = acc;
      }
      __syncthreads();
      if (tid == 0) {
        __builtin_amdgcn_fence(__ATOMIC_RELEASE, "agent");
        __hip_atomic_fetch_add(c_lstm, 1u, __ATOMIC_RELAXED, __HIP_MEMORY_SCOPE_AGENT);
      }
    }
  }
}

__global__ void __launch_bounds__(TPB) final_kernel(float* __restrict__ out) {
  __shared__ float buf[P1];
  __shared__ float red[8];
  const int row = blockIdx.x;
  const int tid = threadIdx.x;
  const int lane = tid & 63, wid = tid >> 6;
  if (row == 0) {
    const float v = -logf((float)P1);
    for (int idx = tid; idx < P1; idx += TPB) out[idx] = v;
    return;
  }
  float* o = out + row * P1;
  for (int idx = tid; idx < P1; idx += TPB) buf[idx] = o[idx];
  __syncthreads();
  float p = 0.0f;
  for (int idx = tid; idx < P1; idx += TPB) p += __expf(buf[idx]);
  p = wave_reduce(p);
  if (lane == 0) red[wid] = p;
  __syncthreads();
  const float s1 = red[0] + red[1] + red[2] + red[3];
  const float inv = __builtin_amdgcn_rcpf(s1);
  __syncthreads();
  float p2 = 0.0f;
  for (int idx = tid; idx < P1; idx += TPB) {
    float be = __expf(buf[idx]) * inv;   // beta
    buf[idx] = be;
    p2 += __expf(be);
  }
  p2 = wave_reduce(p2);
  if (lane == 0) red[wid] = p2;
  __syncthreads();
  const float ls2 = logf(red[0] + red[1] + red[2] + red[3]);
  for (int idx = tid; idx < P1; idx += TPB) o[idx] = buf[idx] - ls2;
}

extern "C" void kernel_launch(void* const* d_in, const int* in_sizes, int n_in,
                              void* d_out, int out_size, void* d_ws, size_t ws_size,
                              hipStream_t stream) {
  (void)in_sizes; (void)n_in; (void)out_size; (void)ws_size;
  const float* H    = (const float*)d_in[0];
  const float* W1   = (const float*)d_in[1];
  const float* W2   = (const float*)d_in[2];
  const float* b2   = (const float*)d_in[3];
  const float* w3   = (const float*)d_in[4];
  const float* c    = (const float*)d_in[5];
  const float* W_ih = (const float*)d_in[6];
  const float* W_hh = (const float*)d_in[7];
  const float* b_ih = (const float*)d_in[8];
  const float* b_hh = (const float*)d_in[9];
  float* out = (float*)d_out;
  float* ws  = (float*)d_ws;

  hipFuncSetAttribute(reinterpret_cast<const void*>(scan_kernel),
                      hipFuncAttributeMaxDynamicSharedMemorySize, 160 * 1024);

  hipLaunchKernelGGL(init_kernel, dim3(1), dim3(TPB), 0, stream, ws);
  hipLaunchKernelGGL(prep_gemm, dim3(17, 20), dim3(256), 0, stream, H, W1, W_ih, ws);
  hipLaunchKernelGGL(scan_kernel, dim3(NBLK), dim3(TPB), DYN_SMEM, stream,
                     W2, b2, w3, c, W_hh, b_ih, b_hh, ws, out);
  hipLaunchKernelGGL(final_kernel, dim3(P1), dim3(TPB), 0, stream, out);
}

// Round 3
// 8015.142 us; speedup vs baseline: 1.6224x; 1.6224x over previous
//
#include <hip/hip_runtime.h>
#include <math.h>

#define L 256
#define P 1024
#define P1 1025
#define TWOL 512
#define FOURL 1024
#define NATT 48
#define NLSTM 16
#define NBLK (NATT + NLSTM)
#define TPB 256

// workspace layout (float units)
#define OFF_VH    0
#define OFF_WHT   (OFF_VH + P1*L)              // 1025*256
#define OFF_GX    (OFF_WHT + P1*FOURL)         // 1025*1024
#define OFF_X2P   (OFF_GX + 2*NATT*FOURL)      // [2][NATT][1024]
#define OFF_HBUF  (OFF_X2P + 2*NLSTM*L)        // [2][NLSTM][256]
#define OFF_SP    (OFF_HBUF + 2*L)             // [2][256]
#define OFF_AFLAG (OFF_SP + 2*NATT)            // [2][48]
#define OFF_LFLAG (OFF_AFLAG + NATT*32)        // 48 flags, 128B strided
#define WS_FLOATS (OFF_LFLAG + NLSTM*32)       // 16 flags, 128B strided

#define DYN_SMEM 118912  // att role: 23*256*4 + 23*1024*4 + 1024 + 128

#define SCOPE_AGENT __HIP_MEMORY_SCOPE_AGENT

__device__ __forceinline__ float ldc(const float* p) {
  return __hip_atomic_load(p, __ATOMIC_RELAXED, SCOPE_AGENT);
}
__device__ __forceinline__ void stc(float* p, float v) {
  __hip_atomic_store(p, v, __ATOMIC_RELAXED, SCOPE_AGENT);
}
__device__ __forceinline__ unsigned ldu(const unsigned* p) {
  return __hip_atomic_load(p, __ATOMIC_RELAXED, SCOPE_AGENT);
}
__device__ __forceinline__ void stu(unsigned* p, unsigned v) {
  __hip_atomic_store(p, v, __ATOMIC_RELAXED, SCOPE_AGENT);
}

__device__ __forceinline__ float fast_tanh(float x) {
  float u = __expf(2.0f * x);
  return 1.0f - 2.0f * __builtin_amdgcn_rcpf(1.0f + u);
}
__device__ __forceinline__ float sigm(float x) {
  return __builtin_amdgcn_rcpf(1.0f + __expf(-x));
}
__device__ __forceinline__ float wave_reduce(float v) {
  #pragma unroll
  for (int o = 32; o > 0; o >>= 1) v += __shfl_xor(v, o, 64);
  return v;
}

__global__ void init_kernel(float* __restrict__ ws) {
  const int tid = threadIdx.x;
  for (int idx = tid; idx < 2 * NLSTM * L; idx += TPB) stc(ws + OFF_X2P + idx, 0.0f);
  for (int idx = tid; idx < 2 * L; idx += TPB)        stc(ws + OFF_HBUF + idx, 0.0f);
  unsigned* fl = (unsigned*)(ws + OFF_AFLAG);
  for (int idx = tid; idx < NATT * 32 + NLSTM * 32; idx += TPB) stu(fl + idx, 0u);
}

// C[j][n] = sum_k H_r[j][k] * W[n][k], with W = [W1 ; W_ih] (N=1280), H_r[1024][:] = 0
__global__ void __launch_bounds__(256) prep_gemm(const float* __restrict__ H,
                                                 const float* __restrict__ W1,
                                                 const float* __restrict__ W_ih,
                                                 float* __restrict__ ws) {
  __shared__ float As[32 * 64];
  __shared__ float Bs[64 * 33];
  const int tid = threadIdx.x;
  const int j0 = blockIdx.x * 64;
  const int n0 = blockIdx.y * 64;
  const int tx = tid & 15, ty = tid >> 4;
  float acc[4][4] = {{0.f,0.f,0.f,0.f},{0.f,0.f,0.f,0.f},{0.f,0.f,0.f,0.f},{0.f,0.f,0.f,0.f}};
  for (int ks = 0; ks < TWOL; ks += 32) {
    for (int idx = tid; idx < 2048; idx += 256) {
      int kk = idx >> 6, jj = idx & 63;
      int j = j0 + jj;
      As[kk * 64 + jj] = (j < P) ? H[(ks + kk) * P + j] : 0.0f;
    }
    for (int idx = tid; idx < 2048; idx += 256) {
      int kk = idx & 31, nn = idx >> 5;
      int n = n0 + nn;
      Bs[nn * 33 + kk] = (n < L) ? W1[n * TWOL + ks + kk] : W_ih[(n - L) * TWOL + ks + kk];
    }
    __syncthreads();
    #pragma unroll
    for (int kk = 0; kk < 32; ++kk) {
      float4 a = *(const float4*)&As[kk * 64 + ty * 4];
      #pragma unroll
      for (int r = 0; r < 4; ++r) {
        float bb = Bs[(tx * 4 + r) * 33 + kk];
        acc[r][0] += a.x * bb; acc[r][1] += a.y * bb;
        acc[r][2] += a.z * bb; acc[r][3] += a.w * bb;
      }
    }
    __syncthreads();
  }
  #pragma unroll
  for (int q = 0; q < 4; ++q) {
    int j = j0 + ty * 4 + q;
    if (j <= P) {
      float4 v = make_float4(acc[0][q], acc[1][q], acc[2][q], acc[3][q]);
      int n = n0 + tx * 4;
      if (n < L) *(float4*)&ws[OFF_VH + j * L + n] = v;
      else       *(float4*)&ws[OFF_WHT + j * FOURL + (n - L)] = v;
    }
  }
}

__global__ void __launch_bounds__(TPB, 1) scan_kernel(
    const float* __restrict__ W2, const float* __restrict__ b2,
    const float* __restrict__ w3, const float* __restrict__ cin,
    const float* __restrict__ W_hh, const float* __restrict__ b_ih,
    const float* __restrict__ b_hh,
    float* __restrict__ ws, float* __restrict__ out) {
  extern __shared__ float smem[];
  const int tid = threadIdx.x;
  const int b = blockIdx.x;
  float* gx   = ws + OFF_GX;
  float* x2p  = ws + OFF_X2P;
  float* hbuf = ws + OFF_HBUF;
  float* sp   = ws + OFF_SP;
  unsigned* aflag = (unsigned*)(ws + OFF_AFLAG);
  unsigned* lflag = (unsigned*)(ws + OFF_LFLAG);
  const int lane = tid & 63, wid = tid >> 6;

  if (b < NATT) {
    // ---------------- attention role ----------------
    int nrows, j0;
    if (b < 32)      { nrows = 21; j0 = 21 * b; }
    else if (b < 47) { nrows = 22; j0 = 672 + 22 * (b - 32); }
    else             { nrows = 23; j0 = 1002; }            // includes terminal j=1024 (zero row)
    float* vh_s  = smem;                  // <=23*256
    float* wht_s = smem + 23 * L;         // <=23*1024
    float* x2_s  = wht_s + 23 * FOURL;    // 256
    float* e_s   = x2_s + L;              // 32
    const float* VH  = ws + OFF_VH;
    const float* WHT = ws + OFF_WHT;
    for (int idx = tid; idx < nrows * L; idx += TPB)     vh_s[idx]  = VH[j0 * L + idx];
    for (int idx = tid; idx < nrows * FOURL; idx += TPB) wht_s[idx] = WHT[j0 * FOURL + idx];
    const float4 w3r = *(const float4*)&w3[4 * lane];
    const float rb2 = b2[tid];
    const float cb = cin[0];
    __syncthreads();

    for (int t = 1; t <= P; ++t) {
      const int par = t & 1;
      if (t > 1) {
        if (wid == 0) {
          const unsigned tgt = (unsigned)(t - 1);
          for (;;) {
            unsigned v = (lane < NLSTM) ? ldu(lflag + lane * 32) : 0xFFFFFFFFu;
            if (__all(v >= tgt)) break;
          }
        }
        __syncthreads();
      }
      {  // x2 = b2 + sum of lstm partials (batched bypass loads)
        const float* xp = x2p + par * NLSTM * L;
        float tmp[NLSTM];
        #pragma unroll
        for (int q = 0; q < NLSTM; ++q) tmp[q] = ldc(xp + q * L + tid);
        float v = rb2;
        #pragma unroll
        for (int q = 0; q < NLSTM; ++q) v += tmp[q];
        x2_s[tid] = v;
      }
      __syncthreads();
      const float4 x2r = *(const float4*)&x2_s[4 * lane];
      for (int r = wid; r < nrows; r += 4) {
        float4 a = *(const float4*)&vh_s[r * L + 4 * lane];
        float s = w3r.x * fast_tanh(a.x + x2r.x);
        s += w3r.y * fast_tanh(a.y + x2r.y);
        s += w3r.z * fast_tanh(a.z + x2r.z);
        s += w3r.w * fast_tanh(a.w + x2r.w);
        s = wave_reduce(s);
        if (lane == 0) {
          float vf = s + cb;
          e_s[r] = __expf(vf);
          out[t * P1 + j0 + r] = vf;   // raw logits; final kernel normalizes (plain store ok: consumed next kernel)
        }
      }
      __syncthreads();
      {  // gate partial: this block's columns' contribution to all 1024 gate rows
        float4 acc = make_float4(0.f, 0.f, 0.f, 0.f);
        for (int r = 0; r < nrows; ++r) {
          float e = e_s[r];
          float4 w = *(const float4*)&wht_s[r * FOURL + 4 * tid];
          acc.x += e * w.x; acc.y += e * w.y; acc.z += e * w.z; acc.w += e * w.w;
        }
        float* gp = gx + (par * NATT + b) * FOURL + 4 * tid;
        stc(gp + 0, acc.x); stc(gp + 1, acc.y); stc(gp + 2, acc.z); stc(gp + 3, acc.w);
      }
      if (wid == 0) {  // S partial
        float e = (lane < nrows) ? e_s[lane] : 0.0f;
        e = wave_reduce(e);
        if (lane == 0) stc(sp + par * NATT + b, e);
      }
      __syncthreads();  // drains vmcnt for ALL threads' stores before flag
      if (tid == 0) stu(aflag + b * 32, (unsigned)t);
    }
  } else {
    // ---------------- lstm role ----------------
    const int lidx = b - NATT;
    const int i0 = 16 * lidx;
    float* whh_s = smem;              // 64*256
    float* w2c_s = whh_s + 64 * L;    // [16][256] transposed (bank-conflict-free)
    float* h_s   = w2c_s + 16 * L;    // 256
    float* hhp_s = h_s + L;           // 256
    float* hh_s  = hhp_s + L;         // 64
    float* gxp_s = hh_s + 64;         // 256
    float* gate_s= gxp_s + L;         // 64
    float* ss_s  = gate_s + 64;       // 16 (S sum)
    float* cc_s  = ss_s + 16;         // 16
    float* hn_s  = cc_s + 16;         // 16
    for (int idx = tid; idx < 64 * L; idx += TPB) {
      int z = idx >> 8, k = idx & 255;
      int gr = (z >> 4) * L + i0 + (z & 15);
      whh_s[idx] = W_hh[gr * L + k];
    }
    for (int idx = tid; idx < 16 * L; idx += TPB) {
      int ii = idx >> 8, i = idx & 255;          // w2c_s[ii][i] = W2[i][i0+ii]
      w2c_s[ii * L + i] = W2[i * L + i0 + ii];
    }
    float biasz = 0.0f;
    if (tid < 64) {
      int gr = (tid >> 4) * L + i0 + (tid & 15);
      biasz = b_ih[gr] + b_hh[gr];
    }
    if (tid < 16) cc_s[tid] = 0.0f;
    __syncthreads();
    const int z = tid & 63, w = tid >> 6;

    for (int t = 1; t <= P; ++t) {
      const int rpar = (t - 1) & 1;   // parity holding h(t-1) / x2p target for t+1
      const int par = t & 1;          // parity of this step's att data
      if (t > 1) {
        if (wid == 0) {
          const unsigned tgt = (unsigned)(t - 1);
          for (;;) {
            unsigned v = (lane < NLSTM) ? ldu(lflag + lane * 32) : 0xFFFFFFFFu;
            if (__all(v >= tgt)) break;
          }
        }
        __syncthreads();
      }
      h_s[tid] = ldc(hbuf + rpar * L + tid);
      __syncthreads();
      {  // hh = W_hh @ h for my 64 gate rows (4 partial chunks, bank-skewed)
        float acc = 0.0f;
        #pragma unroll 8
        for (int m = 0; m < 64; ++m) {
          int k = w * 64 + ((m + z) & 63);
          acc += whh_s[z * L + k] * h_s[k];
        }
        hhp_s[w * 64 + z] = acc;
      }
      __syncthreads();
      if (tid < 64)
        hh_s[tid] = biasz + hhp_s[tid] + hhp_s[64 + tid] + hhp_s[128 + tid] + hhp_s[192 + tid];
      // wait for all attention partials of step t
      if (wid == 0) {
        const unsigned tgt = (unsigned)t;
        for (;;) {
          unsigned v = (lane < NATT) ? ldu(aflag + lane * 32) : 0xFFFFFFFFu;
          if (__all(v >= tgt)) break;
        }
      }
      __syncthreads();
      {  // gather gate partials for my rows (batched bypass loads)
        const float* gxp = gx + par * NATT * FOURL;
        int gr = (z >> 4) * L + i0 + (z & 15);
        float tmp[12];
        #pragma unroll
        for (int q = 0; q < 12; ++q) tmp[q] = ldc(gxp + (12 * w + q) * FOURL + gr);
        float acc = 0.0f;
        #pragma unroll
        for (int q = 0; q < 12; ++q) acc += tmp[q];
        gxp_s[w * 64 + z] = acc;
      }
      if (wid == 0) {  // S = sum of 48 partials
        float sv = (lane < NATT) ? ldc(sp + par * NATT + lane) : 0.0f;
        sv = wave_reduce(sv);
        if (lane == 0) ss_s[0] = sv;
      }
      __syncthreads();
      if (tid < 64) {
        float S = ss_s[0];
        float gxv = gxp_s[tid] + gxp_s[64 + tid] + gxp_s[128 + tid] + gxp_s[192 + tid];
        gate_s[tid] = gxv * __builtin_amdgcn_rcpf(S) + hh_s[tid];
      }
      if (tid < 16) {  // same wave as gate_s writers: in-order LDS within a wave
        float gi = gate_s[tid], gf = gate_s[16 + tid], gg = gate_s[32 + tid], go = gate_s[48 + tid];
        float c_new = sigm(gf) * cc_s[tid] + sigm(gi) * fast_tanh(gg);
        float h_new = sigm(go) * fast_tanh(c_new);
        cc_s[tid] = c_new; hn_s[tid] = h_new;
        stc(hbuf + par * L + i0 + tid, h_new);
      }
      __syncthreads();
      {  // x2 contribution for step t+1 (conflict-free transposed layout)
        float acc = 0.0f;
        #pragma unroll
        for (int ii = 0; ii < 16; ++ii) acc += w2c_s[ii * L + tid] * hn_s[ii];
        stc(x2p + (rpar * NLSTM + lidx) * L + tid, acc);
      }
      __syncthreads();  // drain all bypass stores
      if (tid == 0) stu(lflag + lidx * 32, (unsigned)t);
    }
  }
}

__global__ void __launch_bounds__(TPB) final_kernel(float* __restrict__ out) {
  __shared__ float buf[P1];
  __shared__ float red[8];
  const int row = blockIdx.x;
  const int tid = threadIdx.x;
  const int lane = tid & 63, wid = tid >> 6;
  if (row == 0) {
    const float v = -logf((float)P1);
    for (int idx = tid; idx < P1; idx += TPB) out[idx] = v;
    return;
  }
  float* o = out + row * P1;
  for (int idx = tid; idx < P1; idx += TPB) buf[idx] = o[idx];
  __syncthreads();
  float p = 0.0f;
  for (int idx = tid; idx < P1; idx += TPB) p += __expf(buf[idx]);
  p = wave_reduce(p);
  if (lane == 0) red[wid] = p;
  __syncthreads();
  const float s1 = red[0] + red[1] + red[2] + red[3];
  const float inv = __builtin_amdgcn_rcpf(s1);
  __syncthreads();
  float p2 = 0.0f;
  for (int idx = tid; idx < P1; idx += TPB) {
    float be = __expf(buf[idx]) * inv;   // beta
    buf[idx] = be;
    p2 += __expf(be);
  }
  p2 = wave_reduce(p2);
  if (lane == 0) red[wid] = p2;
  __syncthreads();
  const float ls2 = logf(red[0] + red[1] + red[2] + red[3]);
  for (int idx = tid; idx < P1; idx += TPB) o[idx] = buf[idx] - ls2;
}

extern "C" void kernel_launch(void* const* d_in, const int* in_sizes, int n_in,
                              void* d_out, int out_size, void* d_ws, size_t ws_size,
                              hipStream_t stream) {
  (void)in_sizes; (void)n_in; (void)out_size; (void)ws_size;
  const float* H    = (const float*)d_in[0];
  const float* W1   = (const float*)d_in[1];
  const float* W2   = (const float*)d_in[2];
  const float* b2   = (const float*)d_in[3];
  const float* w3   = (const float*)d_in[4];
  const float* c    = (const float*)d_in[5];
  const float* W_ih = (const float*)d_in[6];
  const float* W_hh = (const float*)d_in[7];
  const float* b_ih = (const float*)d_in[8];
  const float* b_hh = (const float*)d_in[9];
  float* out = (float*)d_out;
  float* ws  = (float*)d_ws;

  hipFuncSetAttribute(reinterpret_cast<const void*>(scan_kernel),
                      hipFuncAttributeMaxDynamicSharedMemorySize, 160 * 1024);

  hipLaunchKernelGGL(init_kernel, dim3(1), dim3(TPB), 0, stream, ws);
  hipLaunchKernelGGL(prep_gemm, dim3(17, 20), dim3(256), 0, stream, H, W1, W_ih, ws);
  hipLaunchKernelGGL(scan_kernel, dim3(NBLK), dim3(TPB), DYN_SMEM, stream,
                     W2, b2, w3, c, W_hh, b_ih, b_hh, ws, out);
  hipLaunchKernelGGL(final_kernel, dim3(P1), dim3(TPB), 0, stream, out);
}